// Round 16
// baseline (198.375 us; speedup 1.0000x reference)
//
#include <hip/hip_runtime.h>

typedef unsigned short u16;
typedef __attribute__((ext_vector_type(8))) short bf16x8;
typedef __attribute__((ext_vector_type(4))) short bf16x4;
typedef __attribute__((ext_vector_type(4))) float f32x4;
typedef __attribute__((ext_vector_type(4))) unsigned short u16x4;
typedef __attribute__((ext_vector_type(2))) unsigned int u32x2;

// Problem constants (fixed by the reference)
#define SEQ 1024
#define BSZ 8
#define NHD 16
#define DHD 64
#define DMODEL 1024

__device__ __forceinline__ u16 f2bf(float x) {
  unsigned u = __float_as_uint(x);
  return (u16)((u + 0x7fffu + ((u >> 16) & 1u)) >> 16);  // RNE
}
__device__ __forceinline__ float bf2f(u16 h) {
  return __uint_as_float(((unsigned)h) << 16);
}

typedef const __attribute__((address_space(1))) unsigned int gu32_t;
typedef __attribute__((address_space(3))) unsigned int lu32_t;
__device__ __forceinline__ void gload16(const void* g, void* l) {
  __builtin_amdgcn_global_load_lds((gu32_t*)g, (lu32_t*)l, 16, 0, 0);
}

// ---------------- merged prep kernel (5 independent input-only transforms) ----------------
// [0,8192): w [i][b][1024] f32 -> w_b BATCH-MAJOR [b][i][1024] bf16 (one row/block).
// [8192,11264): qkv_w [1024][3072] -> [3072][1024] bf16.
// [11264,12288): o_w [1024][1024] -> transposed bf16.  [12288,12800): r_emb -> frag order.
// [12800,12864): cvec c[n][t] = rwb[n].r_emb[t][n].
__global__ void prep_k(const float* __restrict__ w, const float* __restrict__ qkv_w,
                       const float* __restrict__ o_w, const float* __restrict__ r_emb,
                       const float* __restrict__ rwb,
                       u16* __restrict__ w_b, u16* __restrict__ qkvw_t,
                       u16* __restrict__ ow_t, u16* __restrict__ remb_f,
                       float* __restrict__ cvb) {
  __shared__ float tile[32][33];
  const int id = blockIdx.x;
  const int tid = threadIdx.x;
  if (id < 8192) {
    // id = i*8 + b ; dst row = b*1024 + i (batch-major for gemm<0> A)
    const float* src = w + (size_t)id * 1024 + tid * 4;
    u16* dst = w_b + (((size_t)(id & 7) << 10) + (id >> 3)) * 1024 + tid * 4;
    float4 v = *(const float4*)src;
    u16x4 o;
    o[0] = f2bf(v.x); o[1] = f2bf(v.y); o[2] = f2bf(v.z); o[3] = f2bf(v.w);
    *(u16x4*)dst = o;
  } else if (id < 12288) {
    // transpose_cast: qkv_w (R=1024,C=3072) or o_w (R=1024,C=1024)
    const bool isq = id < 11264;
    const int lid = isq ? (id - 8192) : (id - 11264);
    const int C = isq ? 3072 : 1024;
    const int bx = (isq ? (lid % 96) : (lid & 31)) * 32;
    const int by = (isq ? (lid / 96) : (lid >> 5)) * 32;
    const float* in = isq ? qkv_w : o_w;
    u16* out = isq ? qkvw_t : ow_t;
    const int tx = tid & 31, ty = tid >> 5;
#pragma unroll
    for (int rr = ty; rr < 32; rr += 8)
      tile[rr][tx] = in[(size_t)(by + rr) * C + bx + tx];
    __syncthreads();
#pragma unroll
    for (int rr = ty; rr < 32; rr += 8)
      out[(size_t)(bx + rr) * 1024 + by + tx] = f2bf(tile[tx][rr]);
  } else if (id < 12800) {
    int t0 = (id - 12288) * 256 + tid;  // (j*16+n)*8 + db
    int jn = t0 >> 3, db = t0 & 7;
    int j = jn >> 4, n = jn & 15;
    const float* src = r_emb + (size_t)jn * 64 + db * 8;
    u16* dst = remb_f + (size_t)n * 65536 + (size_t)(j >> 4) * 1024 + (db >> 2) * 512 +
               (((j & 15) | ((db & 3) << 4)) << 3);
#pragma unroll
    for (int e = 0; e < 8; ++e) dst[e] = f2bf(src[e]);
  } else {
    int idx = (id - 12800) * 256 + tid;  // n*1024 + t
    int n = idx >> 10, t = idx & 1023;
    const float* src = r_emb + (size_t)(t * 16 + n) * 64;
    const float* wb = rwb + n * 64;
    float s = 0.f;
#pragma unroll
    for (int d = 0; d < 64; ++d) s += src[d] * wb[d];
    cvb[idx] = s;
  }
}

// ---------------- GEMM: C[M,N] = A[M,K] @ Bt[N,K]^T  (bf16, 128x128 tile) ----------------
// 1-D grid with XCD-chunked swizzle (T1). Proven R10 2-buffer double-buffered loop.
// EPI 0: A rows are BATCH-MAJOR (rg = b*1024 + i) so a thread's 4 acc rows are 4
// consecutive i of ONE batch -> dense frag-order scatter (q stride-64 same page,
// V-frag 4 contiguous u16, K-frag within one 1KB group). EPI 1: token-major rows,
// yout = resid + C (f32), unchanged.
template <int EPI>
__global__ __launch_bounds__(256) void gemm_bt(
    const u16* __restrict__ A, const u16* __restrict__ Bt, int K, int nbn,
    u16* __restrict__ q_o, u16* __restrict__ k_o, u16* __restrict__ v_o,
    const float* __restrict__ resid, float* __restrict__ yout) {
  __shared__ __attribute__((aligned(16))) u16 ldsA[2][4096];  // [128 rows][32 k]
  __shared__ __attribute__((aligned(16))) u16 ldsB[2][4096];
  const int tid = threadIdx.x;
  const int wid = tid >> 6, l = tid & 63;
  const int l15 = l & 15, lg = l >> 4;
  // XCD-chunked bijective remap (gridDim.x % 8 == 0 for both uses)
  const int cpx = gridDim.x >> 3;
  const int id0 = blockIdx.x;
  const int lid = (id0 & 7) * cpx + (id0 >> 3);
  const int bm = lid / nbn, bn = lid % nbn;
  const int wm = wid & 1, wn = wid >> 1;
  const size_t ldb = (size_t)K * 2;  // row bytes

  const char* aA = (const char*)A + (size_t)(bm * 128 + wid * 32 + (l >> 2)) * ldb + (l & 3) * 16;
  const char* aB = (const char*)Bt + (size_t)(bn * 128 + wid * 32 + (l >> 2)) * ldb + (l & 3) * 16;

  auto stage = [&](int buf, int kt) {
    const char* sa = aA + (size_t)kt * 64;
    const char* sb = aB + (size_t)kt * 64;
    char* la = (char*)&ldsA[buf][wid * 1024];
    char* lb = (char*)&ldsB[buf][wid * 1024];
    gload16(sa, la);
    gload16(sa + 16 * ldb, la + 1024);
    gload16(sb, lb);
    gload16(sb + 16 * ldb, lb + 1024);
  };

  f32x4 acc[4][4] = {};
  stage(0, 0);
  __syncthreads();
  const int NT = K >> 5;
  for (int t = 0; t < NT; ++t) {
    int cur = t & 1;
    if (t + 1 < NT) stage(cur ^ 1, t + 1);
    bf16x8 af[4], bfr[4];
#pragma unroll
    for (int mi = 0; mi < 4; ++mi)
      af[mi] = *(const bf16x8*)&ldsA[cur][(wm * 64 + mi * 16 + l15) * 32 + lg * 8];
#pragma unroll
    for (int ni = 0; ni < 4; ++ni)
      bfr[ni] = *(const bf16x8*)&ldsB[cur][(wn * 64 + ni * 16 + l15) * 32 + lg * 8];
#pragma unroll
    for (int mi = 0; mi < 4; ++mi)
#pragma unroll
      for (int ni = 0; ni < 4; ++ni)
        acc[mi][ni] = __builtin_amdgcn_mfma_f32_16x16x32_bf16(af[mi], bfr[ni], acc[mi][ni], 0, 0, 0);
    __syncthreads();
  }

  if (EPI == 0) {
#pragma unroll
    for (int mi = 0; mi < 4; ++mi)
#pragma unroll
      for (int ni = 0; ni < 4; ++ni) {
        int c = bn * 128 + wn * 64 + ni * 16 + l15;
        int which = c >> 10, rem = c & 1023, h = rem >> 6, d = rem & 63;
        u16* dst = which == 0 ? q_o : (which == 1 ? k_o : v_o);
#pragma unroll
        for (int r = 0; r < 4; ++r) {
          int rg = bm * 128 + wm * 64 + mi * 16 + lg * 4 + r;
          int bb = rg >> 10, i = rg & 1023;   // batch-major A rows
          int bn2 = bb * 16 + h;
          size_t idx;
          if (which == 0) {
            idx = ((size_t)bn2 * 1024 + i) * 64 + d;
          } else if (which == 1) {
            // K frag: [bn][j16][ks][lane][8]
            idx = (size_t)bn2 * 65536 + (size_t)(i >> 4) * 1024 + (d >> 5) * 512 +
                  (((i & 15) | (((d >> 3) & 3) << 4)) << 3) + (d & 7);
          } else {
            // V frag: [bn][j16][dd][lane][4]
            idx = (size_t)bn2 * 65536 + (size_t)(i >> 4) * 1024 + (d >> 4) * 256 +
                  (((d & 15) | (((i >> 2) & 3) << 4)) << 2) + (i & 3);
          }
          dst[idx] = f2bf(acc[mi][ni][r]);
        }
      }
  } else {
#pragma unroll
    for (int mi = 0; mi < 4; ++mi)
#pragma unroll
      for (int ni = 0; ni < 4; ++ni) {
        int c = bn * 128 + wn * 64 + ni * 16 + l15;
#pragma unroll
        for (int r = 0; r < 4; ++r) {
          int rg = bm * 128 + wm * 64 + mi * 16 + lg * 4 + r;
          size_t off = (size_t)rg * 1024 + c;
          yout[off] = resid[off] + acc[mi][ni][r];
        }
      }
  }
}

// ---------------- fused causal rel-attention (barrier-free, 32 q-rows/wave) ----------
// Block: 64 q-rows (2 waves x 32 rows as 2x16 subgroups A/B), KV tiles of 64.
// Grid 2048, longest-first. Subgroups SHARE K/V fragments; 6 r_emb frags cover
// both E windows. Barrier-free loop, per-wave njt.
// Fixed-offset softmax: p = 2^( SC*(AC+B+D) - 16 ), offset exact, divides out.
// rb PAD = -1e30 implements the causal mask through the E path (t>=1024 <=> j>i).
// Softmax denominator l computed by ONES-MFMA (row sums in acc layout).
__global__ __launch_bounds__(128, 3) void attn_k(
    const u16* __restrict__ qg, const u16* __restrict__ kf, const u16* __restrict__ vf,
    const u16* __restrict__ rf, const float* __restrict__ rbias,
    const float* __restrict__ cvec, const float* __restrict__ rwb,
    u16* __restrict__ av) {
  __shared__ __attribute__((aligned(16))) float EldsA[2][16][84];
  __shared__ __attribute__((aligned(16))) float EldsB[2][16][84];
  __shared__ __attribute__((aligned(16))) float rb[1088];

  const int tid = threadIdx.x;
  const int wid = tid >> 6, l = tid & 63;
  const int l15 = l & 15, lg = l >> 4;
  const int id = blockIdx.x;
  const int qblk = 15 - (id >> 7);   // longest-first dispatch (64 rows/block)
  const int n = (id & 7) | (((id >> 3) & 1) << 3);  // id%8 keys head%8 (XCD grouping)
  const int b = (id >> 4) & 7;
  const int bn = b * 16 + n;
  const int ib = qblk * 64;
  const int iw = ib + wid * 32;      // wave base: subgroup A rows iw.., B rows iw+16..

  const float SC = 0.18033688011f;   // 0.125 * log2(e)

  // rb = SC*(rbias - cvec) - 16 ; pad (t>=1024 <=> causal-masked) = -1e30
  for (int idx = tid; idx < 1088; idx += 128)
    rb[idx] = (idx < 1024) ? (SC * (rbias[idx * 16 + n] - cvec[n * 1024 + idx]) - 16.0f)
                           : -1e30f;

  // Q fragment sets (r_w_bias folded, SC pre-scaled), one per subgroup
  const float* wbp = rwb + n * 64;
  const u16* qrowA = qg + ((size_t)bn * 1024 + iw + l15) * 64;
  const u16* qrowB = qrowA + 16 * 64;
  bf16x8 qa0 = *(const bf16x8*)(qrowA + lg * 8);
  bf16x8 qa1 = *(const bf16x8*)(qrowA + 32 + lg * 8);
  bf16x8 qb0 = *(const bf16x8*)(qrowB + lg * 8);
  bf16x8 qb1 = *(const bf16x8*)(qrowB + 32 + lg * 8);
  bf16x8 qwA0, qwA1, qwB0, qwB1;
#pragma unroll
  for (int e = 0; e < 8; ++e) {
    float w0 = wbp[lg * 8 + e], w1 = wbp[32 + lg * 8 + e];
    qwA0[e] = (short)f2bf(SC * (bf2f((u16)qa0[e]) + w0));
    qwA1[e] = (short)f2bf(SC * (bf2f((u16)qa1[e]) + w1));
    qwB0[e] = (short)f2bf(SC * (bf2f((u16)qb0[e]) + w0));
    qwB1[e] = (short)f2bf(SC * (bf2f((u16)qb1[e]) + w1));
  }

  f32x4 oaccA[4] = {}, oaccB[4] = {};
  f32x4 lsA = {}, lsB = {};          // row-sum accumulators (ones-MFMA)
  bf16x4 ones;
  ones[0] = ones[1] = ones[2] = ones[3] = (short)0x3F80;  // bf16 1.0

  // per-lane fragment pointers (lane-major frag layouts, fully coalesced)
  const u16* kfp = kf + (size_t)bn * 65536 + l * 8;
  const u16* vfp = vf + (size_t)bn * 65536 + l * 4;
  const u16* rfp = rf + (size_t)n * 65536 + l * 8;

  __syncthreads();  // rb visible (the only barrier)

  const int njt = (iw >> 6) + 1;     // per-wave tile count (barrier-free)
  for (int jt = 0; jt < njt; ++jt) {
    const int jb = jt * 64;

    // ---- K fragments: 8 coalesced 1KB loads (shared by A and B) ----
    const u16* kt = kfp + jt * 4096;
    bf16x8 kk[8];
#pragma unroll
    for (int s = 0; s < 8; ++s) kk[s] = *(const bf16x8*)(kt + s * 512);

    // ---- E phase: 6 frags cover both subgroups' windows; f32x4 stores ----
    const int tbB = jb - iw - 16 + 1008;  // subgroup B window base (A = tbB+16)
    const int t16b = tbB >> 4;
#pragma unroll
    for (int f = 0; f < 6; ++f) {
      int t16 = t16b + f;
      if (t16 > 63) t16 = 63;  // >1023 rows are masked (rb pad = -1e30) anyway
      const u16* rr = rfp + t16 * 1024;
      bf16x8 ra0 = *(const bf16x8*)(rr);
      bf16x8 ra1 = *(const bf16x8*)(rr + 512);
      f32x4 rb4 = *(const f32x4*)&rb[tbB + f * 16 + lg * 4];
      if (f < 5) {
        f32x4 et = {};
        et = __builtin_amdgcn_mfma_f32_16x16x32_bf16(ra0, qwB0, et, 0, 0, 0);
        et = __builtin_amdgcn_mfma_f32_16x16x32_bf16(ra1, qwB1, et, 0, 0, 0);
        *(f32x4*)&EldsB[wid][l15][f * 16 + lg * 4] = et + rb4;
      }
      if (f >= 1) {
        f32x4 et = {};
        et = __builtin_amdgcn_mfma_f32_16x16x32_bf16(ra0, qwA0, et, 0, 0, 0);
        et = __builtin_amdgcn_mfma_f32_16x16x32_bf16(ra1, qwA1, et, 0, 0, 0);
        *(f32x4*)&EldsA[wid][l15][(f - 1) * 16 + lg * 4] = et + rb4;
      }
    }

    // ---- S^T = K.qw for both subgroups (K regs shared, then dead) ----
    f32x4 stA[4], stB[4];
    __builtin_amdgcn_s_setprio(1);
#pragma unroll
    for (int jj = 0; jj < 4; ++jj) {
      f32x4 a = __builtin_amdgcn_mfma_f32_16x16x32_bf16(kk[jj * 2], qwA0, (f32x4){}, 0, 0, 0);
      stA[jj] = __builtin_amdgcn_mfma_f32_16x16x32_bf16(kk[jj * 2 + 1], qwA1, a, 0, 0, 0);
    }
#pragma unroll
    for (int jj = 0; jj < 4; ++jj) {
      f32x4 a = __builtin_amdgcn_mfma_f32_16x16x32_bf16(kk[jj * 2], qwB0, (f32x4){}, 0, 0, 0);
      stB[jj] = __builtin_amdgcn_mfma_f32_16x16x32_bf16(kk[jj * 2 + 1], qwB1, a, 0, 0, 0);
    }
    __builtin_amdgcn_s_setprio(0);

    // ---- V fragments: 16 coalesced 512B loads (shared; hide under softmax) ----
    const u16* vt0 = vfp + jt * 4096;
    bf16x4 vv[4][4];
#pragma unroll
    for (int jj = 0; jj < 4; ++jj)
#pragma unroll
      for (int dd = 0; dd < 4; ++dd)
        vv[jj][dd] = *(const bf16x4*)(vt0 + jj * 1024 + dd * 256);

    // ---- softmax: p = 2^(st + E); mask & offset pre-folded; no reductions ----
    bf16x4 paA[4], paB[4];
#pragma unroll
    for (int jj = 0; jj < 4; ++jj) {
      const int ebase = jj * 16 + lg * 4 - l15 + 15;
      {
        float v0 = stA[jj][0] + EldsA[wid][l15][ebase + 0];
        float v1 = stA[jj][1] + EldsA[wid][l15][ebase + 1];
        float v2 = stA[jj][2] + EldsA[wid][l15][ebase + 2];
        float v3 = stA[jj][3] + EldsA[wid][l15][ebase + 3];
        float p0, p1, p2, p3;
        asm("v_exp_f32 %0, %1" : "=v"(p0) : "v"(v0));
        asm("v_exp_f32 %0, %1" : "=v"(p1) : "v"(v1));
        asm("v_exp_f32 %0, %1" : "=v"(p2) : "v"(v2));
        asm("v_exp_f32 %0, %1" : "=v"(p3) : "v"(v3));
        unsigned lo, hi;
        asm("v_cvt_pk_bf16_f32 %0, %1, %2" : "=v"(lo) : "v"(p0), "v"(p1));
        asm("v_cvt_pk_bf16_f32 %0, %1, %2" : "=v"(hi) : "v"(p2), "v"(p3));
        u32x2 t2; t2[0] = lo; t2[1] = hi;
        paA[jj] = __builtin_bit_cast(bf16x4, t2);
      }
      {
        float v0 = stB[jj][0] + EldsB[wid][l15][ebase + 0];
        float v1 = stB[jj][1] + EldsB[wid][l15][ebase + 1];
        float v2 = stB[jj][2] + EldsB[wid][l15][ebase + 2];
        float v3 = stB[jj][3] + EldsB[wid][l15][ebase + 3];
        float p0, p1, p2, p3;
        asm("v_exp_f32 %0, %1" : "=v"(p0) : "v"(v0));
        asm("v_exp_f32 %0, %1" : "=v"(p1) : "v"(v1));
        asm("v_exp_f32 %0, %1" : "=v"(p2) : "v"(v2));
        asm("v_exp_f32 %0, %1" : "=v"(p3) : "v"(v3));
        unsigned lo, hi;
        asm("v_cvt_pk_bf16_f32 %0, %1, %2" : "=v"(lo) : "v"(p0), "v"(p1));
        asm("v_cvt_pk_bf16_f32 %0, %1, %2" : "=v"(hi) : "v"(p2), "v"(p3));
        u32x2 t2; t2[0] = lo; t2[1] = hi;
        paB[jj] = __builtin_bit_cast(bf16x4, t2);
      }
    }

    // ---- PV + l row-sums (ones-MFMA); P is the 16x16x16 A-fragment ----
    __builtin_amdgcn_s_setprio(1);
#pragma unroll
    for (int dd = 0; dd < 4; ++dd)
#pragma unroll
      for (int jj = 0; jj < 4; ++jj)
        oaccA[dd] = __builtin_amdgcn_mfma_f32_16x16x16bf16_1k(paA[jj], vv[jj][dd], oaccA[dd], 0, 0, 0);
#pragma unroll
    for (int jj = 0; jj < 4; ++jj)
      lsA = __builtin_amdgcn_mfma_f32_16x16x16bf16_1k(paA[jj], ones, lsA, 0, 0, 0);
#pragma unroll
    for (int dd = 0; dd < 4; ++dd)
#pragma unroll
      for (int jj = 0; jj < 4; ++jj)
        oaccB[dd] = __builtin_amdgcn_mfma_f32_16x16x16bf16_1k(paB[jj], vv[jj][dd], oaccB[dd], 0, 0, 0);
#pragma unroll
    for (int jj = 0; jj < 4; ++jj)
      lsB = __builtin_amdgcn_mfma_f32_16x16x16bf16_1k(paB[jj], ones, lsB, 0, 0, 0);
    __builtin_amdgcn_s_setprio(0);
  }

  // ls[r2] = l for q-row (iw + lg*4 + r2) — same layout as oacc rows, no shuffles
#pragma unroll
  for (int dd = 0; dd < 4; ++dd)
#pragma unroll
    for (int r2 = 0; r2 < 4; ++r2) {
      int igA = iw + lg * 4 + r2;
      av[((size_t)igA * 8 + b) * 1024 + n * 64 + dd * 16 + l15] = f2bf(oaccA[dd][r2] / lsA[r2]);
      int igB = igA + 16;
      av[((size_t)igB * 8 + b) * 1024 + n * 64 + dd * 16 + l15] = f2bf(oaccB[dd][r2] / lsB[r2]);
    }
}

// ---------------- in-place LayerNorm over rows of 1024 ----------------
__global__ void ln_k(float* __restrict__ y, const float* __restrict__ g,
                     const float* __restrict__ be) {
  const int row = blockIdx.x, tid = threadIdx.x;
  float* p = y + (size_t)row * 1024;
  float4 v = ((const float4*)p)[tid];
  float s1 = v.x + v.y + v.z + v.w;
  float s2 = v.x * v.x + v.y * v.y + v.z * v.z + v.w * v.w;
#pragma unroll
  for (int mk = 1; mk < 64; mk <<= 1) {
    s1 += __shfl_xor(s1, mk);
    s2 += __shfl_xor(s2, mk);
  }
  __shared__ float as1[4], as2[4];
  if ((tid & 63) == 0) { as1[tid >> 6] = s1; as2[tid >> 6] = s2; }
  __syncthreads();
  s1 = as1[0] + as1[1] + as1[2] + as1[3];
  s2 = as2[0] + as2[1] + as2[2] + as2[3];
  float mu = s1 * (1.f / 1024.f);
  float var = s2 * (1.f / 1024.f) - mu * mu;
  float rs = rsqrtf(var + 1e-5f);
  float4 gg = ((const float4*)g)[tid];
  float4 bb = ((const float4*)be)[tid];
  float4 o;
  o.x = (v.x - mu) * rs * gg.x + bb.x;
  o.y = (v.y - mu) * rs * gg.y + bb.y;
  o.z = (v.z - mu) * rs * gg.z + bb.z;
  o.w = (v.w - mu) * rs * gg.w + bb.w;
  ((float4*)p)[tid] = o;
}

extern "C" void kernel_launch(void* const* d_in, const int* in_sizes, int n_in,
                              void* d_out, int out_size, void* d_ws, size_t ws_size,
                              hipStream_t stream) {
  (void)in_sizes; (void)n_in; (void)out_size; (void)ws_size;
  const float* w      = (const float*)d_in[0];
  const float* r_emb  = (const float*)d_in[1];
  const float* r_wb   = (const float*)d_in[2];
  const float* r_bias = (const float*)d_in[3];
  const float* qkv_w  = (const float*)d_in[4];
  const float* o_w    = (const float*)d_in[5];
  const float* ln_g   = (const float*)d_in[6];
  const float* ln_b   = (const float*)d_in[7];
  float* out = (float*)d_out;
  char* ws = (char*)d_ws;

  // workspace layout (bytes); total ~77.7 MB
  u16* w_b    = (u16*)(ws + 0);          // 16 MB batch-major; reused as attn_vec after
  u16* qkvw_t = (u16*)(ws + 16777216);   // 6 MB  [3072][1024]
  u16* ow_t   = (u16*)(ws + 23068672);   // 2 MB  [1024][1024]
  u16* remb_f = (u16*)(ws + 25165824);   // 2 MB  frag order [n][t16][ks][lane][8]
  u16* q_b    = (u16*)(ws + 27262976);   // 16 MB [b][h][i][d]
  u16* k_f    = (u16*)(ws + 44040192);   // 16 MB frag order [bn][j16][ks][lane][8]
  u16* v_f    = (u16*)(ws + 60817408);   // 16 MB frag order [bn][j16][dd][lane][4]
  float* cvb  = (float*)(ws + 77594624); // 64 KB [n][t]
  u16* av_b   = w_b;

  prep_k<<<dim3(12864), 256, 0, stream>>>(w, qkv_w, o_w, r_emb, r_wb,
                                          w_b, qkvw_t, ow_t, remb_f, cvb);
  gemm_bt<0><<<dim3(1536), 256, 0, stream>>>(w_b, qkvw_t, 1024, 24, q_b, k_f, v_f, nullptr, nullptr);
  attn_k<<<dim3(2048), 128, 0, stream>>>(q_b, k_f, v_f, remb_f, r_bias, cvb, r_wb, av_b);
  gemm_bt<1><<<dim3(512), 256, 0, stream>>>(av_b, ow_t, 1024, 8, nullptr, nullptr, nullptr, w, out);
  ln_k<<<8192, 256, 0, stream>>>(out, ln_g, ln_b);
}

// Round 17
// 191.313 us; speedup vs baseline: 1.0369x; 1.0369x over previous
//
#include <hip/hip_runtime.h>

typedef unsigned short u16;
typedef __attribute__((ext_vector_type(8))) short bf16x8;
typedef __attribute__((ext_vector_type(4))) short bf16x4;
typedef __attribute__((ext_vector_type(4))) float f32x4;
typedef __attribute__((ext_vector_type(4))) unsigned short u16x4;
typedef __attribute__((ext_vector_type(2))) unsigned int u32x2;

// Problem constants (fixed by the reference)
#define SEQ 1024
#define BSZ 8
#define NHD 16
#define DHD 64
#define DMODEL 1024

__device__ __forceinline__ u16 f2bf(float x) {
  unsigned u = __float_as_uint(x);
  return (u16)((u + 0x7fffu + ((u >> 16) & 1u)) >> 16);  // RNE
}
__device__ __forceinline__ float bf2f(u16 h) {
  return __uint_as_float(((unsigned)h) << 16);
}

typedef const __attribute__((address_space(1))) unsigned int gu32_t;
typedef __attribute__((address_space(3))) unsigned int lu32_t;
__device__ __forceinline__ void gload16(const void* g, void* l) {
  __builtin_amdgcn_global_load_lds((gu32_t*)g, (lu32_t*)l, 16, 0, 0);
}

// ---------------- merged prep kernel (5 independent input-only transforms) ----------------
// [0,8192): w f32 -> bf16.  [8192,11264): qkv_w [1024][3072] -> [3072][1024] bf16.
// [11264,12288): o_w [1024][1024] -> transposed bf16.  [12288,12800): r_emb -> frag order.
// [12800,12864): cvec c[n][t] = rwb[n].r_emb[t][n].
__global__ void prep_k(const float* __restrict__ w, const float* __restrict__ qkv_w,
                       const float* __restrict__ o_w, const float* __restrict__ r_emb,
                       const float* __restrict__ rwb,
                       u16* __restrict__ w_b, u16* __restrict__ qkvw_t,
                       u16* __restrict__ ow_t, u16* __restrict__ remb_f,
                       float* __restrict__ cvb) {
  __shared__ float tile[32][33];
  const int id = blockIdx.x;
  const int tid = threadIdx.x;
  if (id < 8192) {
    size_t i = ((size_t)id * 256 + tid) * 4;
    float4 v = *(const float4*)(w + i);
    u16x4 o;
    o[0] = f2bf(v.x); o[1] = f2bf(v.y); o[2] = f2bf(v.z); o[3] = f2bf(v.w);
    *(u16x4*)(w_b + i) = o;
  } else if (id < 12288) {
    // transpose_cast: qkv_w (R=1024,C=3072) or o_w (R=1024,C=1024)
    const bool isq = id < 11264;
    const int lid = isq ? (id - 8192) : (id - 11264);
    const int C = isq ? 3072 : 1024;
    const int bx = (isq ? (lid % 96) : (lid & 31)) * 32;
    const int by = (isq ? (lid / 96) : (lid >> 5)) * 32;
    const float* in = isq ? qkv_w : o_w;
    u16* out = isq ? qkvw_t : ow_t;
    const int tx = tid & 31, ty = tid >> 5;
#pragma unroll
    for (int rr = ty; rr < 32; rr += 8)
      tile[rr][tx] = in[(size_t)(by + rr) * C + bx + tx];
    __syncthreads();
#pragma unroll
    for (int rr = ty; rr < 32; rr += 8)
      out[(size_t)(bx + rr) * 1024 + by + tx] = f2bf(tile[tx][rr]);
  } else if (id < 12800) {
    int t0 = (id - 12288) * 256 + tid;  // (j*16+n)*8 + db
    int jn = t0 >> 3, db = t0 & 7;
    int j = jn >> 4, n = jn & 15;
    const float* src = r_emb + (size_t)jn * 64 + db * 8;
    u16* dst = remb_f + (size_t)n * 65536 + (size_t)(j >> 4) * 1024 + (db >> 2) * 512 +
               (((j & 15) | ((db & 3) << 4)) << 3);
#pragma unroll
    for (int e = 0; e < 8; ++e) dst[e] = f2bf(src[e]);
  } else {
    int idx = (id - 12800) * 256 + tid;  // n*1024 + t
    int n = idx >> 10, t = idx & 1023;
    const float* src = r_emb + (size_t)(t * 16 + n) * 64;
    const float* wb = rwb + n * 64;
    float s = 0.f;
#pragma unroll
    for (int d = 0; d < 64; ++d) s += src[d] * wb[d];
    cvb[idx] = s;
  }
}

// ---------------- GEMM: C[M,N] = A[M,K] @ Bt[N,K]^T  (bf16, 128x128 tile) ----------------
// 1-D grid with XCD-chunked swizzle (T1). Proven R10 2-buffer double-buffered
// loop (counted-vmcnt, LDS-repack, V-pair scatter, write-layout all regressed).
// EPI 0: scatter q normal [b][h][i][d]; K and V in MFMA-fragment order.
// EPI 1: yout = resid + C (f32).
template <int EPI>
__global__ __launch_bounds__(256) void gemm_bt(
    const u16* __restrict__ A, const u16* __restrict__ Bt, int K, int nbn,
    u16* __restrict__ q_o, u16* __restrict__ k_o, u16* __restrict__ v_o,
    const float* __restrict__ resid, float* __restrict__ yout) {
  __shared__ __attribute__((aligned(16))) u16 ldsA[2][4096];  // [128 rows][32 k]
  __shared__ __attribute__((aligned(16))) u16 ldsB[2][4096];
  const int tid = threadIdx.x;
  const int wid = tid >> 6, l = tid & 63;
  const int l15 = l & 15, lg = l >> 4;
  // XCD-chunked bijective remap (gridDim.x % 8 == 0 for both uses)
  const int cpx = gridDim.x >> 3;
  const int id0 = blockIdx.x;
  const int lid = (id0 & 7) * cpx + (id0 >> 3);
  const int bm = lid / nbn, bn = lid % nbn;
  const int wm = wid & 1, wn = wid >> 1;
  const size_t ldb = (size_t)K * 2;  // row bytes

  const char* aA = (const char*)A + (size_t)(bm * 128 + wid * 32 + (l >> 2)) * ldb + (l & 3) * 16;
  const char* aB = (const char*)Bt + (size_t)(bn * 128 + wid * 32 + (l >> 2)) * ldb + (l & 3) * 16;

  auto stage = [&](int buf, int kt) {
    const char* sa = aA + (size_t)kt * 64;
    const char* sb = aB + (size_t)kt * 64;
    char* la = (char*)&ldsA[buf][wid * 1024];
    char* lb = (char*)&ldsB[buf][wid * 1024];
    gload16(sa, la);
    gload16(sa + 16 * ldb, la + 1024);
    gload16(sb, lb);
    gload16(sb + 16 * ldb, lb + 1024);
  };

  f32x4 acc[4][4] = {};
  stage(0, 0);
  __syncthreads();
  const int NT = K >> 5;
  for (int t = 0; t < NT; ++t) {
    int cur = t & 1;
    if (t + 1 < NT) stage(cur ^ 1, t + 1);
    bf16x8 af[4], bfr[4];
#pragma unroll
    for (int mi = 0; mi < 4; ++mi)
      af[mi] = *(const bf16x8*)&ldsA[cur][(wm * 64 + mi * 16 + l15) * 32 + lg * 8];
#pragma unroll
    for (int ni = 0; ni < 4; ++ni)
      bfr[ni] = *(const bf16x8*)&ldsB[cur][(wn * 64 + ni * 16 + l15) * 32 + lg * 8];
#pragma unroll
    for (int mi = 0; mi < 4; ++mi)
#pragma unroll
      for (int ni = 0; ni < 4; ++ni)
        acc[mi][ni] = __builtin_amdgcn_mfma_f32_16x16x32_bf16(af[mi], bfr[ni], acc[mi][ni], 0, 0, 0);
    __syncthreads();
  }

  if (EPI == 0) {
#pragma unroll
    for (int mi = 0; mi < 4; ++mi)
#pragma unroll
      for (int ni = 0; ni < 4; ++ni) {
        int c = bn * 128 + wn * 64 + ni * 16 + l15;
        int which = c >> 10, rem = c & 1023, h = rem >> 6, d = rem & 63;
        u16* dst = which == 0 ? q_o : (which == 1 ? k_o : v_o);
#pragma unroll
        for (int r = 0; r < 4; ++r) {
          int rg = bm * 128 + wm * 64 + mi * 16 + lg * 4 + r;
          int i = rg >> 3, bb = rg & 7;
          int bn2 = bb * 16 + h;
          size_t idx;
          if (which == 0) {
            idx = ((size_t)bn2 * 1024 + i) * 64 + d;
          } else if (which == 1) {
            // K frag: [bn][j16][ks][lane][8]
            idx = (size_t)bn2 * 65536 + (size_t)(i >> 4) * 1024 + (d >> 5) * 512 +
                  (((i & 15) | (((d >> 3) & 3) << 4)) << 3) + (d & 7);
          } else {
            // V frag: [bn][j16][dd][lane][4]
            idx = (size_t)bn2 * 65536 + (size_t)(i >> 4) * 1024 + (d >> 4) * 256 +
                  (((d & 15) | (((i >> 2) & 3) << 4)) << 2) + (i & 3);
          }
          dst[idx] = f2bf(acc[mi][ni][r]);
        }
      }
  } else {
#pragma unroll
    for (int mi = 0; mi < 4; ++mi)
#pragma unroll
      for (int ni = 0; ni < 4; ++ni) {
        int c = bn * 128 + wn * 64 + ni * 16 + l15;
#pragma unroll
        for (int r = 0; r < 4; ++r) {
          int rg = bm * 128 + wm * 64 + mi * 16 + lg * 4 + r;
          size_t off = (size_t)rg * 1024 + c;
          yout[off] = resid[off] + acc[mi][ni][r];
        }
      }
  }
}

// ---------------- fused causal rel-attention (barrier-free, 32 q-rows/wave) ----------
// Block: 64 q-rows (2 waves x 32 rows as 2x16 subgroups A/B), KV tiles of 64.
// Grid 2048, longest-first. Subgroups SHARE K/V fragments; 6 r_emb frags cover
// both E windows. Barrier-free loop, per-wave njt.
// Fixed-offset softmax: p = 2^( SC*(AC+B+D) - 16 ), offset exact, divides out.
// rb PAD = -1e30 implements the causal mask through the E path (t>=1024 <=> j>i).
// Softmax denominator l computed by ONES-MFMA: P (A-frag layout) x ones-B gives
// exact row sums; acc layout row=lg*4+reg matches the io[] indexing directly ->
// removes 32 VALU adds/tile and ALL end-of-kernel shuffles (VALU -> MFMA pipe).
__global__ __launch_bounds__(128, 3) void attn_k(
    const u16* __restrict__ qg, const u16* __restrict__ kf, const u16* __restrict__ vf,
    const u16* __restrict__ rf, const float* __restrict__ rbias,
    const float* __restrict__ cvec, const float* __restrict__ rwb,
    u16* __restrict__ av) {
  __shared__ __attribute__((aligned(16))) float EldsA[2][16][84];
  __shared__ __attribute__((aligned(16))) float EldsB[2][16][84];
  __shared__ __attribute__((aligned(16))) float rb[1088];

  const int tid = threadIdx.x;
  const int wid = tid >> 6, l = tid & 63;
  const int l15 = l & 15, lg = l >> 4;
  const int id = blockIdx.x;
  const int qblk = 15 - (id >> 7);   // longest-first dispatch (64 rows/block)
  const int n = (id & 7) | (((id >> 3) & 1) << 3);  // id%8 keys head%8 (XCD grouping)
  const int b = (id >> 4) & 7;
  const int bn = b * 16 + n;
  const int ib = qblk * 64;
  const int iw = ib + wid * 32;      // wave base: subgroup A rows iw.., B rows iw+16..

  const float SC = 0.18033688011f;   // 0.125 * log2(e)

  // rb = SC*(rbias - cvec) - 16 ; pad (t>=1024 <=> causal-masked) = -1e30
  for (int idx = tid; idx < 1088; idx += 128)
    rb[idx] = (idx < 1024) ? (SC * (rbias[idx * 16 + n] - cvec[n * 1024 + idx]) - 16.0f)
                           : -1e30f;

  // Q fragment sets (r_w_bias folded, SC pre-scaled), one per subgroup
  const float* wbp = rwb + n * 64;
  const u16* qrowA = qg + ((size_t)bn * 1024 + iw + l15) * 64;
  const u16* qrowB = qrowA + 16 * 64;
  bf16x8 qa0 = *(const bf16x8*)(qrowA + lg * 8);
  bf16x8 qa1 = *(const bf16x8*)(qrowA + 32 + lg * 8);
  bf16x8 qb0 = *(const bf16x8*)(qrowB + lg * 8);
  bf16x8 qb1 = *(const bf16x8*)(qrowB + 32 + lg * 8);
  bf16x8 qwA0, qwA1, qwB0, qwB1;
#pragma unroll
  for (int e = 0; e < 8; ++e) {
    float w0 = wbp[lg * 8 + e], w1 = wbp[32 + lg * 8 + e];
    qwA0[e] = (short)f2bf(SC * (bf2f((u16)qa0[e]) + w0));
    qwA1[e] = (short)f2bf(SC * (bf2f((u16)qa1[e]) + w1));
    qwB0[e] = (short)f2bf(SC * (bf2f((u16)qb0[e]) + w0));
    qwB1[e] = (short)f2bf(SC * (bf2f((u16)qb1[e]) + w1));
  }

  f32x4 oaccA[4] = {}, oaccB[4] = {};
  f32x4 lsA = {}, lsB = {};          // row-sum accumulators (ones-MFMA)
  bf16x4 ones;
  ones[0] = ones[1] = ones[2] = ones[3] = (short)0x3F80;  // bf16 1.0

  // per-lane fragment pointers (lane-major frag layouts, fully coalesced)
  const u16* kfp = kf + (size_t)bn * 65536 + l * 8;
  const u16* vfp = vf + (size_t)bn * 65536 + l * 4;
  const u16* rfp = rf + (size_t)n * 65536 + l * 8;

  __syncthreads();  // rb visible (the only barrier)

  const int njt = (iw >> 6) + 1;     // per-wave tile count (barrier-free)
  for (int jt = 0; jt < njt; ++jt) {
    const int jb = jt * 64;

    // ---- K fragments: 8 coalesced 1KB loads (shared by A and B) ----
    const u16* kt = kfp + jt * 4096;
    bf16x8 kk[8];
#pragma unroll
    for (int s = 0; s < 8; ++s) kk[s] = *(const bf16x8*)(kt + s * 512);

    // ---- E phase: 6 frags cover both subgroups' windows; f32x4 stores ----
    const int tbB = jb - iw - 16 + 1008;  // subgroup B window base (A = tbB+16)
    const int t16b = tbB >> 4;
#pragma unroll
    for (int f = 0; f < 6; ++f) {
      int t16 = t16b + f;
      if (t16 > 63) t16 = 63;  // >1023 rows are masked (rb pad = -1e30) anyway
      const u16* rr = rfp + t16 * 1024;
      bf16x8 ra0 = *(const bf16x8*)(rr);
      bf16x8 ra1 = *(const bf16x8*)(rr + 512);
      f32x4 rb4 = *(const f32x4*)&rb[tbB + f * 16 + lg * 4];
      if (f < 5) {
        f32x4 et = {};
        et = __builtin_amdgcn_mfma_f32_16x16x32_bf16(ra0, qwB0, et, 0, 0, 0);
        et = __builtin_amdgcn_mfma_f32_16x16x32_bf16(ra1, qwB1, et, 0, 0, 0);
        *(f32x4*)&EldsB[wid][l15][f * 16 + lg * 4] = et + rb4;
      }
      if (f >= 1) {
        f32x4 et = {};
        et = __builtin_amdgcn_mfma_f32_16x16x32_bf16(ra0, qwA0, et, 0, 0, 0);
        et = __builtin_amdgcn_mfma_f32_16x16x32_bf16(ra1, qwA1, et, 0, 0, 0);
        *(f32x4*)&EldsA[wid][l15][(f - 1) * 16 + lg * 4] = et + rb4;
      }
    }

    // ---- S^T = K.qw for both subgroups (K regs shared, then dead) ----
    f32x4 stA[4], stB[4];
    __builtin_amdgcn_s_setprio(1);
#pragma unroll
    for (int jj = 0; jj < 4; ++jj) {
      f32x4 a = __builtin_amdgcn_mfma_f32_16x16x32_bf16(kk[jj * 2], qwA0, (f32x4){}, 0, 0, 0);
      stA[jj] = __builtin_amdgcn_mfma_f32_16x16x32_bf16(kk[jj * 2 + 1], qwA1, a, 0, 0, 0);
    }
#pragma unroll
    for (int jj = 0; jj < 4; ++jj) {
      f32x4 a = __builtin_amdgcn_mfma_f32_16x16x32_bf16(kk[jj * 2], qwB0, (f32x4){}, 0, 0, 0);
      stB[jj] = __builtin_amdgcn_mfma_f32_16x16x32_bf16(kk[jj * 2 + 1], qwB1, a, 0, 0, 0);
    }
    __builtin_amdgcn_s_setprio(0);

    // ---- V fragments: 16 coalesced 512B loads (shared; hide under softmax) ----
    const u16* vt0 = vfp + jt * 4096;
    bf16x4 vv[4][4];
#pragma unroll
    for (int jj = 0; jj < 4; ++jj)
#pragma unroll
      for (int dd = 0; dd < 4; ++dd)
        vv[jj][dd] = *(const bf16x4*)(vt0 + jj * 1024 + dd * 256);

    // ---- softmax: p = 2^(st + E); mask & offset pre-folded; no reductions ----
    bf16x4 paA[4], paB[4];
#pragma unroll
    for (int jj = 0; jj < 4; ++jj) {
      const int ebase = jj * 16 + lg * 4 - l15 + 15;
      {
        float v0 = stA[jj][0] + EldsA[wid][l15][ebase + 0];
        float v1 = stA[jj][1] + EldsA[wid][l15][ebase + 1];
        float v2 = stA[jj][2] + EldsA[wid][l15][ebase + 2];
        float v3 = stA[jj][3] + EldsA[wid][l15][ebase + 3];
        float p0, p1, p2, p3;
        asm("v_exp_f32 %0, %1" : "=v"(p0) : "v"(v0));
        asm("v_exp_f32 %0, %1" : "=v"(p1) : "v"(v1));
        asm("v_exp_f32 %0, %1" : "=v"(p2) : "v"(v2));
        asm("v_exp_f32 %0, %1" : "=v"(p3) : "v"(v3));
        unsigned lo, hi;
        asm("v_cvt_pk_bf16_f32 %0, %1, %2" : "=v"(lo) : "v"(p0), "v"(p1));
        asm("v_cvt_pk_bf16_f32 %0, %1, %2" : "=v"(hi) : "v"(p2), "v"(p3));
        u32x2 t2; t2[0] = lo; t2[1] = hi;
        paA[jj] = __builtin_bit_cast(bf16x4, t2);
      }
      {
        float v0 = stB[jj][0] + EldsB[wid][l15][ebase + 0];
        float v1 = stB[jj][1] + EldsB[wid][l15][ebase + 1];
        float v2 = stB[jj][2] + EldsB[wid][l15][ebase + 2];
        float v3 = stB[jj][3] + EldsB[wid][l15][ebase + 3];
        float p0, p1, p2, p3;
        asm("v_exp_f32 %0, %1" : "=v"(p0) : "v"(v0));
        asm("v_exp_f32 %0, %1" : "=v"(p1) : "v"(v1));
        asm("v_exp_f32 %0, %1" : "=v"(p2) : "v"(v2));
        asm("v_exp_f32 %0, %1" : "=v"(p3) : "v"(v3));
        unsigned lo, hi;
        asm("v_cvt_pk_bf16_f32 %0, %1, %2" : "=v"(lo) : "v"(p0), "v"(p1));
        asm("v_cvt_pk_bf16_f32 %0, %1, %2" : "=v"(hi) : "v"(p2), "v"(p3));
        u32x2 t2; t2[0] = lo; t2[1] = hi;
        paB[jj] = __builtin_bit_cast(bf16x4, t2);
      }
    }

    // ---- PV + l row-sums (ones-MFMA); P is the 16x16x16 A-fragment ----
    __builtin_amdgcn_s_setprio(1);
#pragma unroll
    for (int dd = 0; dd < 4; ++dd)
#pragma unroll
      for (int jj = 0; jj < 4; ++jj)
        oaccA[dd] = __builtin_amdgcn_mfma_f32_16x16x16bf16_1k(paA[jj], vv[jj][dd], oaccA[dd], 0, 0, 0);
#pragma unroll
    for (int jj = 0; jj < 4; ++jj)
      lsA = __builtin_amdgcn_mfma_f32_16x16x16bf16_1k(paA[jj], ones, lsA, 0, 0, 0);
#pragma unroll
    for (int dd = 0; dd < 4; ++dd)
#pragma unroll
      for (int jj = 0; jj < 4; ++jj)
        oaccB[dd] = __builtin_amdgcn_mfma_f32_16x16x16bf16_1k(paB[jj], vv[jj][dd], oaccB[dd], 0, 0, 0);
#pragma unroll
    for (int jj = 0; jj < 4; ++jj)
      lsB = __builtin_amdgcn_mfma_f32_16x16x16bf16_1k(paB[jj], ones, lsB, 0, 0, 0);
    __builtin_amdgcn_s_setprio(0);
  }

  // ls[r2] = l for q-row (iw + lg*4 + r2) — same layout as oacc rows, no shuffles
#pragma unroll
  for (int dd = 0; dd < 4; ++dd)
#pragma unroll
    for (int r2 = 0; r2 < 4; ++r2) {
      int igA = iw + lg * 4 + r2;
      av[((size_t)igA * 8 + b) * 1024 + n * 64 + dd * 16 + l15] = f2bf(oaccA[dd][r2] / lsA[r2]);
      int igB = igA + 16;
      av[((size_t)igB * 8 + b) * 1024 + n * 64 + dd * 16 + l15] = f2bf(oaccB[dd][r2] / lsB[r2]);
    }
}

// ---------------- in-place LayerNorm over rows of 1024 ----------------
__global__ void ln_k(float* __restrict__ y, const float* __restrict__ g,
                     const float* __restrict__ be) {
  const int row = blockIdx.x, tid = threadIdx.x;
  float* p = y + (size_t)row * 1024;
  float4 v = ((const float4*)p)[tid];
  float s1 = v.x + v.y + v.z + v.w;
  float s2 = v.x * v.x + v.y * v.y + v.z * v.z + v.w * v.w;
#pragma unroll
  for (int mk = 1; mk < 64; mk <<= 1) {
    s1 += __shfl_xor(s1, mk);
    s2 += __shfl_xor(s2, mk);
  }
  __shared__ float as1[4], as2[4];
  if ((tid & 63) == 0) { as1[tid >> 6] = s1; as2[tid >> 6] = s2; }
  __syncthreads();
  s1 = as1[0] + as1[1] + as1[2] + as1[3];
  s2 = as2[0] + as2[1] + as2[2] + as2[3];
  float mu = s1 * (1.f / 1024.f);
  float var = s2 * (1.f / 1024.f) - mu * mu;
  float rs = rsqrtf(var + 1e-5f);
  float4 gg = ((const float4*)g)[tid];
  float4 bb = ((const float4*)be)[tid];
  float4 o;
  o.x = (v.x - mu) * rs * gg.x + bb.x;
  o.y = (v.y - mu) * rs * gg.y + bb.y;
  o.z = (v.z - mu) * rs * gg.z + bb.z;
  o.w = (v.w - mu) * rs * gg.w + bb.w;
  ((float4*)p)[tid] = o;
}

extern "C" void kernel_launch(void* const* d_in, const int* in_sizes, int n_in,
                              void* d_out, int out_size, void* d_ws, size_t ws_size,
                              hipStream_t stream) {
  (void)in_sizes; (void)n_in; (void)out_size; (void)ws_size;
  const float* w      = (const float*)d_in[0];
  const float* r_emb  = (const float*)d_in[1];
  const float* r_wb   = (const float*)d_in[2];
  const float* r_bias = (const float*)d_in[3];
  const float* qkv_w  = (const float*)d_in[4];
  const float* o_w    = (const float*)d_in[5];
  const float* ln_g   = (const float*)d_in[6];
  const float* ln_b   = (const float*)d_in[7];
  float* out = (float*)d_out;
  char* ws = (char*)d_ws;

  // workspace layout (bytes); total ~77.7 MB
  u16* w_b    = (u16*)(ws + 0);          // 16 MB; reused as attn_vec after QKV GEMM
  u16* qkvw_t = (u16*)(ws + 16777216);   // 6 MB  [3072][1024]
  u16* ow_t   = (u16*)(ws + 23068672);   // 2 MB  [1024][1024]
  u16* remb_f = (u16*)(ws + 25165824);   // 2 MB  frag order [n][t16][ks][lane][8]
  u16* q_b    = (u16*)(ws + 27262976);   // 16 MB [b][h][i][d]
  u16* k_f    = (u16*)(ws + 44040192);   // 16 MB frag order [bn][j16][ks][lane][8]
  u16* v_f    = (u16*)(ws + 60817408);   // 16 MB frag order [bn][j16][dd][lane][4]
  float* cvb  = (float*)(ws + 77594624); // 64 KB [n][t]
  u16* av_b   = w_b;

  prep_k<<<dim3(12864), 256, 0, stream>>>(w, qkv_w, o_w, r_emb, r_wb,
                                          w_b, qkvw_t, ow_t, remb_f, cvb);
  gemm_bt<0><<<dim3(1536), 256, 0, stream>>>(w_b, qkvw_t, 1024, 24, q_b, k_f, v_f, nullptr, nullptr);
  attn_k<<<dim3(2048), 128, 0, stream>>>(q_b, k_f, v_f, remb_f, r_bias, cvb, r_wb, av_b);
  gemm_bt<1><<<dim3(512), 256, 0, stream>>>(av_b, ow_t, 1024, 8, nullptr, nullptr, nullptr, w, out);
  ln_k<<<8192, 256, 0, stream>>>(out, ln_g, ln_b);
}